// Round 5
// baseline (13840.588 us; speedup 1.0000x reference)
//
#include <hip/hip_runtime.h>
#include <hip/hip_bf16.h>

// MultiLayerLSTM on MI355X: persistent pipelined 2-layer LSTM.
// fp16 MFMA 16x16x32, weights register-resident, fence-free cross-block sync
// via device-coherent (sc0 sc1) relaxed-agent atomics for h rings + flags.

typedef _Float16 f16;
typedef __attribute__((ext_vector_type(8))) _Float16 f16x8;
typedef __attribute__((ext_vector_type(4))) _Float16 f16x4;
typedef __attribute__((ext_vector_type(4))) float f32x4;

#define T_STEPS 2048
#define NBLK 32   // blocks per layer

// ---------------- prep kernels ----------------

__global__ void k_conv_x(const float* __restrict__ x, f16* __restrict__ xf) {
  int i = (blockIdx.x * 256 + threadIdx.x) * 4;
  float4 v = *(const float4*)(x + i);
  f16x4 o; o[0] = (f16)v.x; o[1] = (f16)v.y; o[2] = (f16)v.z; o[3] = (f16)v.w;
  *(f16x4*)(xf + i) = o;
}

// Pack [W_ih; W_hh] columns for block nb into per-(block,wave,kt,nt,lane)
// fp16 MFMA B-fragment order. k map: k = kt*32 + (lane>>4)*8 + j -- identical
// map used for A fragments, so intra-lane k permutation cancels in the MFMA.
template<int KTW, int KI>
__global__ void k_pack(const float* __restrict__ wih, const float* __restrict__ whh,
                       f16* __restrict__ dst) {
  int chunk = blockIdx.x * 256 + threadIdx.x;
  int lane = chunk & 63;
  int x = chunk >> 6;
  int nt = x & 3; x >>= 2;
  int ktl = x % KTW; x /= KTW;
  int w = x & 3; int nb = x >> 2;
  int k0 = (w * KTW + ktl) * 32 + ((lane >> 4) * 8);
  int cl = nt * 16 + (lane & 15);
  int wcol = (cl >> 4) * 512 + nb * 16 + (cl & 15);
  f16x8 v;
#pragma unroll
  for (int j = 0; j < 8; ++j) {
    int k = k0 + j;
    float s = (k < KI) ? wih[(size_t)k * 2048 + wcol]
                       : whh[(size_t)(k - KI) * 2048 + wcol];
    v[j] = (f16)s;
  }
  *(f16x8*)(dst + (size_t)chunk * 8) = v;
}

__global__ void k_init(const float* __restrict__ h0in, f16* h0h, f16* h1h,
                       int* flags0, int* flags1) {
  int tid = threadIdx.x;
  for (int i = tid; i < 16384; i += 256) {
    h0h[i] = (f16)h0in[i];            // layer0 h_0  [32][512]
    h1h[i] = (f16)h0in[16384 + i];    // layer1 h_0
  }
  if (tid == 0) { flags0[0] = NBLK; flags1[0] = NBLK; }
}

// ---------------- persistent recurrence ----------------

__device__ __forceinline__ void spin(const int* f) {
  while (__hip_atomic_load(f, __ATOMIC_RELAXED, __HIP_MEMORY_SCOPE_AGENT) < NBLK) {}
}

__device__ __forceinline__ unsigned long long cohload8(const f16* p) {
  return __hip_atomic_load((const unsigned long long*)p, __ATOMIC_RELAXED,
                           __HIP_MEMORY_SCOPE_AGENT);
}

template<int LAYER>
__device__ __forceinline__ void lstm_body(
    int nb, float* red,
    const f16* __restrict__ xf, f16* h0h, f16* h1h,
    const f16* __restrict__ wp, const float* __restrict__ bias,
    const float* __restrict__ c0, float* out,
    int* flags0, int* flags1)
{
  constexpr int KTW = (LAYER == 0) ? 6 : 8;   // K=768 / 1024, split over 4 waves
  const int tid = threadIdx.x;
  const int w = tid >> 6;
  const int lane = tid & 63;
  const int rowA = lane & 15;
  const int ko = (lane >> 4) * 8;

  // ---- weights -> registers
  f16x8 wf[KTW][4];
  {
    const f16* base = wp + (size_t)((nb * 4 + w) * KTW) * (4 * 64 * 8);
#pragma unroll
    for (int ktl = 0; ktl < KTW; ++ktl)
#pragma unroll
      for (int nt = 0; nt < 4; ++nt)
        wf[ktl][nt] = *(const f16x8*)(base + ((ktl * 4 + nt) * 64 + lane) * 8);
  }

  // ---- ownership: thread owns cells (row_o, hc0) and (row_o, hc0+1)
  const int row_o = tid >> 3;
  const int hc0 = (tid & 7) * 2;
  const int mt_o = row_o >> 4, rg = (row_o & 15) >> 2, rr = row_o & 3;
  float creg[2], bgate[2][4], hlast[2] = {0.f, 0.f};
#pragma unroll
  for (int s = 0; s < 2; ++s) {
    creg[s] = c0[(LAYER * 32 + row_o) * 512 + nb * 16 + hc0 + s];
#pragma unroll
    for (int g = 0; g < 4; ++g) bgate[s][g] = bias[g * 512 + nb * 16 + hc0 + s];
  }

  int* myflags = (LAYER == 0) ? flags0 : flags1;

  for (int t = 1; t <= T_STEPS; ++t) {
    // ---- per-wave dependency spin (no broadcast barrier)
    if (LAYER == 0) {
      if (w == 0) { if (t > 16) spin(flags1 + (t - 16)); }  // h0-ring guard
      else spin(flags0 + (t - 1));
    } else {
      if (w < 2) spin(flags0 + t);
      else spin(flags1 + (t - 1));
    }
    asm volatile("" ::: "memory");

    const int slot0p = ((t - 1) & 15) * 16384;
    const int slot0c = (t & 15) * 16384;
    const int slot1p = ((t - 1) & 3) * 16384;

    f32x4 acc[2][4];
#pragma unroll
    for (int mt = 0; mt < 2; ++mt)
#pragma unroll
      for (int nt = 0; nt < 4; ++nt)
        acc[mt][nt] = (f32x4){0.f, 0.f, 0.f, 0.f};

    // ---- K-split MFMA; x via cached loads, h rings via coherent 8B loads
#pragma unroll
    for (int ktl = 0; ktl < KTW; ++ktl) {
      const int tb = w * KTW + ktl;     // 32-wide k-tile index
      f16x8 a[2];
#pragma unroll
      for (int mt = 0; mt < 2; ++mt) {
        const int r = mt * 16 + rowA;
        if (LAYER == 0 && tb < 8) {
          a[mt] = *(const f16x8*)(xf + (size_t)r * (T_STEPS * 256)
                                  + (size_t)(t - 1) * 256 + tb * 32 + ko);
        } else {
          const f16* p;
          if (LAYER == 0)
            p = h0h + slot0p + r * 512 + (tb * 32 - 256 + ko);
          else
            p = (tb < 16) ? h0h + slot0c + r * 512 + tb * 32 + ko
                          : h1h + slot1p + r * 512 + (tb - 16) * 32 + ko;
          union { unsigned long long q[2]; f16x8 v; } u;
          u.q[0] = cohload8(p);
          u.q[1] = cohload8(p + 4);
          a[mt] = u.v;
        }
      }
#pragma unroll
      for (int nt = 0; nt < 4; ++nt) {
        acc[0][nt] = __builtin_amdgcn_mfma_f32_16x16x32_f16(a[0], wf[ktl][nt], acc[0][nt], 0, 0, 0);
        acc[1][nt] = __builtin_amdgcn_mfma_f32_16x16x32_f16(a[1], wf[ktl][nt], acc[1][nt], 0, 0, 0);
      }
    }

    // ---- cross-wave K reduction through LDS
#pragma unroll
    for (int mt = 0; mt < 2; ++mt)
#pragma unroll
      for (int nt = 0; nt < 4; ++nt)
        *(f32x4*)&red[((((w * 2 + mt) * 4 + nt) * 64) + lane) * 4] = acc[mt][nt];
    __syncthreads();

    // ---- gates + state update (C/D: col=lane&15, row=(lane>>4)*4+reg)
    float hval[2];
#pragma unroll
    for (int s = 0; s < 2; ++s) {
      const int hc = hc0 + s;
      float gv[4];
#pragma unroll
      for (int g = 0; g < 4; ++g) {
        float v = bgate[s][g];
#pragma unroll
        for (int ww = 0; ww < 4; ++ww)
          v += red[((((ww * 2 + mt_o) * 4 + g) * 64) + rg * 16 + hc) * 4 + rr];
        gv[g] = v;
      }
      float ig = 1.f / (1.f + __expf(-gv[0]));
      float fg = 1.f / (1.f + __expf(-gv[1]));
      float gg = tanhf(gv[2]);
      float og = 1.f / (1.f + __expf(-gv[3]));
      float c = fg * creg[s] + ig * gg;
      creg[s] = c;
      float h = og * tanhf(c);
      hval[s] = h; hlast[s] = h;
      if (LAYER == 1)
        __builtin_nontemporal_store(h, out + (size_t)row_o * (T_STEPS * 512)
                                    + (size_t)(t - 1) * 512 + nb * 16 + hc);
    }

    // ---- packed coherent h store (2 f16 -> one 4B agent store)
    {
      f16 l = (f16)hval[0], hgh = (f16)hval[1];
      unsigned int pv = (unsigned int)__builtin_bit_cast(unsigned short, l)
                      | ((unsigned int)__builtin_bit_cast(unsigned short, hgh) << 16);
      f16* dst = ((LAYER == 0) ? (h0h + slot0c) : (h1h + (t & 3) * 16384))
               + row_o * 512 + nb * 16 + hc0;
      __hip_atomic_store((unsigned int*)dst, pv, __ATOMIC_RELAXED,
                         __HIP_MEMORY_SCOPE_AGENT);
    }

    // ---- publish: barrier drains vmcnt (stores acked at coherence point)
    __syncthreads();
    if (tid == 0)
      __hip_atomic_fetch_add(myflags + t, 1, __ATOMIC_RELAXED,
                             __HIP_MEMORY_SCOPE_AGENT);
  }

  // ---- final h_T, c_T (layer 1 only)
  if (LAYER == 1) {
#pragma unroll
    for (int s = 0; s < 2; ++s) {
      out[(size_t)(32 * T_STEPS * 512) + row_o * 512 + nb * 16 + hc0 + s] = hlast[s];
      out[(size_t)(32 * T_STEPS * 512) + 16384 + row_o * 512 + nb * 16 + hc0 + s] = creg[s];
    }
  }
}

__global__ __launch_bounds__(256, 1) void lstm_persist(
    const f16* __restrict__ xf, f16* h0h, f16* h1h,
    const f16* __restrict__ wp0, const f16* __restrict__ wp1,
    const float* __restrict__ b0, const float* __restrict__ b1,
    const float* __restrict__ c0, float* out,
    int* flags0, int* flags1)
{
  __shared__ float red[4 * 2 * 4 * 64 * 4];   // 32 KB
  int bid = blockIdx.x;
  if (bid < 32)
    lstm_body<0>(bid, red, xf, h0h, h1h, wp0, b0, c0, out, flags0, flags1);
  else
    lstm_body<1>(bid - 32, red, xf, h0h, h1h, wp1, b1, c0, out, flags0, flags1);
}

// ---------------- launch ----------------

extern "C" void kernel_launch(void* const* d_in, const int* in_sizes, int n_in,
                              void* d_out, int out_size, void* d_ws, size_t ws_size,
                              hipStream_t stream) {
  const float* x    = (const float*)d_in[0];
  const float* h0   = (const float*)d_in[1];
  const float* c0   = (const float*)d_in[2];
  const float* Wih0 = (const float*)d_in[3];
  const float* Whh0 = (const float*)d_in[4];
  const float* b0   = (const float*)d_in[5];
  const float* Wih1 = (const float*)d_in[6];
  const float* Whh1 = (const float*)d_in[7];
  const float* b1   = (const float*)d_in[8];
  float* out = (float*)d_out;
  char* ws = (char*)d_ws;

  // ws layout (bytes), total ~41.7 MB
  f16* xf  = (f16*)(ws);                 // 33,554,432  x as fp16 [B][T][I]
  f16* h0h = (f16*)(ws + 33554432);      //    524,288  h0 ring, 16 slots [32][512]
  f16* h1h = (f16*)(ws + 34078720);      //    131,072  h1 ring, 4 slots
  f16* wp0 = (f16*)(ws + 34209792);      //  3,145,728  packed [Wih0;Whh0]
  f16* wp1 = (f16*)(ws + 37355520);      //  4,194,304  packed [Wih1;Whh1]
  int* flags0 = (int*)(ws + 41549824);   //  arrival counters [t]
  int* flags1 = (int*)(ws + 41582848);

  hipMemsetAsync(ws + 41549824, 0, 66048, stream);
  k_conv_x<<<16384, 256, 0, stream>>>(x, xf);
  k_pack<6, 256><<<768, 256, 0, stream>>>(Wih0, Whh0, wp0);
  k_pack<8, 512><<<1024, 256, 0, stream>>>(Wih1, Whh1, wp1);
  k_init<<<1, 256, 0, stream>>>(h0, h0h, h1h, flags0, flags1);
  lstm_persist<<<64, 256, 0, stream>>>(xf, h0h, h1h, wp0, wp1, b0, b1, c0, out,
                                       flags0, flags1);
}